// Round 4
// baseline (296.478 us; speedup 1.0000x reference)
//
#include <hip/hip_runtime.h>

// Problem constants (from reference)
#define HW    256   // input spatial
#define PH    64    // pooled H (HW/PATCH)
#define PW    64
#define CIN   32
#define NB    4
#define NNODE 4096  // PH*PW
#define EPS_W 1e-6f

typedef float f32x4 __attribute__((ext_vector_type(4)));

// ---------------------------------------------------------------------------
// Kernel 1: per-patch channel-sum S[b, r, cc] = sum_c mean_{4x4}(x_feat)
//           and certainty XV[b, r, cc] = 1 - mean_{4x4}(x_var)
// grid: NB*PH blocks (one pooled row each), 256 threads = 4 waves.
// ---------------------------------------------------------------------------
__global__ __launch_bounds__(256) void pool_kernel(
    const float* __restrict__ x_feat, const float* __restrict__ x_var,
    float* __restrict__ S, float* __restrict__ XV) {
    const int blk  = blockIdx.x;        // b*PH + r
    const int b    = blk >> 6;
    const int r    = blk & 63;
    const int lane = threadIdx.x & 63;
    const int wave = threadIdx.x >> 6;

    __shared__ float red[256];

    float acc = 0.f;
    #pragma unroll
    for (int c = 0; c < 8; ++c) {
        const int ch = wave * 8 + c;
        const float4* p =
            (const float4*)(x_feat + (((size_t)(b * CIN + ch) * HW + r * 4) * HW)) + lane;
        #pragma unroll
        for (int pr = 0; pr < 4; ++pr) {
            float4 v = p[pr * (HW / 4)];
            acc += v.x + v.y + v.z + v.w;
        }
    }
    red[threadIdx.x] = acc;
    __syncthreads();

    if (wave == 0) {
        float s = red[lane] + red[lane + 64] + red[lane + 128] + red[lane + 192];
        S[(b << 12) + (r << 6) + lane] = s * (1.0f / 16.0f);
    } else if (wave == 1) {
        const float4* p = (const float4*)(x_var + ((size_t)b * HW + r * 4) * HW) + lane;
        float a = 0.f;
        #pragma unroll
        for (int pr = 0; pr < 4; ++pr) {
            float4 v = p[pr * (HW / 4)];
            a += v.x + v.y + v.z + v.w;
        }
        XV[(b << 12) + (r << 6) + lane] = 1.0f - a * (1.0f / 16.0f);
    }
}

// ---------------------------------------------------------------------------
// Kernel 2: nodes output. nodes_flat[b*131072 + g] = S[b, g & 4095].
// grid: 512 x 256 = 131072 threads (exact, one float4 each; 2 MB write).
// ---------------------------------------------------------------------------
__global__ __launch_bounds__(256) void nodes_kernel(
    const float* __restrict__ S, float* __restrict__ out) {
    const int i = blockIdx.x * blockDim.x + threadIdx.x;  // float4 index
    const int b = i >> 15;
    const int g = i & 32767;
    f32x4 v = ((const f32x4*)S)[(b << 10) + (g & 1023)];
    __builtin_nontemporal_store(v, (f32x4*)out + i);
}

// ---------------------------------------------------------------------------
// Kernel 3: fused zero+values streaming write of adj.
// Row `from` has <= 4 nonzero cols (from+-1 with row-boundary check, from+-64),
// value xv[from]-xv[col] if > EPS; else 0. Grid-stride: 2048 blocks x 256
// threads x 32 float4 = 16,777,216 float4 = 268 MB written exactly once.
// Consecutive lanes -> consecutive float4 each iteration (coalesced 1 KiB/wave).
// 32 waves/CU occupancy; 4x unroll for outstanding stores.
// ---------------------------------------------------------------------------
__global__ __launch_bounds__(256) void adj_kernel(
    const float* __restrict__ XV, float* __restrict__ adj) {
    const int tid     = blockIdx.x * blockDim.x + threadIdx.x;  // 0..524287
    const int nthread = 2048 * 256;

    #pragma unroll 4
    for (int it = 0; it < 32; ++it) {
        const int i    = tid + it * nthread;   // float4 index, < 2^24
        const int b    = i >> 22;              // 4096*1024 float4 per batch
        const int rem  = i & 4194303;
        const int from = rem >> 10;            // adj row
        const int c0   = (rem & 1023) << 2;    // first col of this float4

        f32x4 v = (f32x4)(0.f);

        // Nonzero cols lie in [from-64, from+64]; float4 covers [c0, c0+3].
        if (c0 >= from - 67 && c0 <= from + 64) {
            const float* xvb = XV + (b << 12);
            const float  xvf = xvb[from];
            #pragma unroll
            for (int j = 0; j < 4; ++j) {
                const int col = c0 + j;
                const int d   = from - col;
                const bool nb = (d == 64) | (d == -64) |
                                ((d == 1)  & ((from & 63) != 0)) |
                                ((d == -1) & ((from & 63) != 63));
                if (nb) {
                    float diff = xvf - xvb[col];
                    v[j] = diff > EPS_W ? diff : 0.f;
                }
            }
        }
        __builtin_nontemporal_store(v, (f32x4*)adj + i);
    }
}

extern "C" void kernel_launch(void* const* d_in, const int* in_sizes, int n_in,
                              void* d_out, int out_size, void* d_ws, size_t ws_size,
                              hipStream_t stream) {
    const float* x_feat = (const float*)d_in[0];  // (4,32,256,256) fp32
    const float* x_var  = (const float*)d_in[1];  // (4,1,256,256) fp32
    float* out = (float*)d_out;                   // nodes (524288) ++ adj (67108864)

    float* S  = (float*)d_ws;            // NB*NNODE floats
    float* XV = S + NB * NNODE;          // NB*NNODE floats  (total 128 KiB ws)

    pool_kernel<<<NB * PH, 256, 0, stream>>>(x_feat, x_var, S, XV);
    nodes_kernel<<<512, 256, 0, stream>>>(S, out);
    adj_kernel<<<2048, 256, 0, stream>>>(XV, out + (size_t)NB * CIN * NNODE);
}

// Round 5
// 282.669 us; speedup vs baseline: 1.0489x; 1.0489x over previous
//
#include <hip/hip_runtime.h>

// Problem constants (from reference)
#define HW    256   // input spatial
#define PH    64    // pooled H (HW/PATCH)
#define PW    64
#define CIN   32
#define NB    4
#define NNODE 4096  // PH*PW
#define EPS_W 1e-6f

#define NODES_F4 131072   // NB*CIN*NNODE/4: float4 count of nodes region
#define TOTAL_F4 16908288 // NODES_F4 + NB*NNODE*NNODE/4

typedef float f32x4 __attribute__((ext_vector_type(4)));

// ---------------------------------------------------------------------------
// Kernel 1: per-patch channel-sum S[b, r, cc] = sum_c mean_{4x4}(x_feat)
//           and certainty XV[b, r, cc] = 1 - mean_{4x4}(x_var)
// grid: NB*PH blocks (one pooled row each), 256 threads = 4 waves.
// Wave w handles channels [8w,8w+8); lane l owns pooled column l.
// Coalesced: 64 lanes x float4 = 1 KiB per load.
// ---------------------------------------------------------------------------
__global__ __launch_bounds__(256) void pool_kernel(
    const float* __restrict__ x_feat, const float* __restrict__ x_var,
    float* __restrict__ S, float* __restrict__ XV) {
    const int blk  = blockIdx.x;        // b*PH + r
    const int b    = blk >> 6;
    const int r    = blk & 63;
    const int lane = threadIdx.x & 63;
    const int wave = threadIdx.x >> 6;

    __shared__ float red[256];

    float acc = 0.f;
    #pragma unroll
    for (int c = 0; c < 8; ++c) {
        const int ch = wave * 8 + c;
        const float4* p =
            (const float4*)(x_feat + (((size_t)(b * CIN + ch) * HW + r * 4) * HW)) + lane;
        #pragma unroll
        for (int pr = 0; pr < 4; ++pr) {
            float4 v = p[pr * (HW / 4)];
            acc += v.x + v.y + v.z + v.w;
        }
    }
    red[threadIdx.x] = acc;
    __syncthreads();

    if (wave == 0) {
        float s = red[lane] + red[lane + 64] + red[lane + 128] + red[lane + 192];
        S[(b << 12) + (r << 6) + lane] = s * (1.0f / 16.0f);
    } else if (wave == 1) {
        const float4* p = (const float4*)(x_var + ((size_t)b * HW + r * 4) * HW) + lane;
        float a = 0.f;
        #pragma unroll
        for (int pr = 0; pr < 4; ++pr) {
            float4 v = p[pr * (HW / 4)];
            a += v.x + v.y + v.z + v.w;
        }
        XV[(b << 12) + (r << 6) + lane] = 1.0f - a * (1.0f / 16.0f);
    }
}

// ---------------------------------------------------------------------------
// Kernel 2: fused writer for the ENTIRE out buffer (270.5 MB), one float4
// per thread, fully dense 1:1 mapping (R3's best-performing store pattern).
//   i <  NODES_F4 : nodes_flat[b*131072+g] = S[b, g & 4095]   (2 MB)
//   i >= NODES_F4 : adj row `from` has <=4 nonzero cols (from+-1 with
//                   row-boundary validity, from+-64); value xv[from]-xv[col]
//                   if > EPS; else 0.  (268 MB, written exactly once)
// Blocks 0..511 are pure-nodes; 512.. are pure-adj (uniform branch per block).
// grid: 66048 x 256 = TOTAL_F4 threads exactly.
// ---------------------------------------------------------------------------
__global__ __launch_bounds__(256) void out_kernel(
    const float* __restrict__ S, const float* __restrict__ XV,
    float* __restrict__ out) {
    const int i = blockIdx.x * blockDim.x + threadIdx.x;  // float4 index

    if (i < NODES_F4) {
        const int b = i >> 15;
        const int g = i & 32767;
        f32x4 v = ((const f32x4*)S)[(b << 10) + (g & 1023)];
        __builtin_nontemporal_store(v, (f32x4*)out + i);
        return;
    }

    const int ia   = i - NODES_F4;       // adj float4 index
    const int b    = ia >> 22;           // 4096*1024 float4 per batch
    const int rem  = ia & 4194303;
    const int from = rem >> 10;          // adj row
    const int c0   = (rem & 1023) << 2;  // first col of this float4

    f32x4 v = (f32x4)(0.f);

    // Nonzero cols lie in [from-64, from+64]; this float4 covers [c0, c0+3].
    if (c0 >= from - 67 && c0 <= from + 64) {
        const float* xvb = XV + (b << 12);
        const float  xvf = xvb[from];
        #pragma unroll
        for (int j = 0; j < 4; ++j) {
            const int col = c0 + j;
            const int d   = from - col;
            const bool nb = (d == 64) | (d == -64) |
                            ((d == 1)  & ((from & 63) != 0)) |
                            ((d == -1) & ((from & 63) != 63));
            if (nb) {
                float diff = xvf - xvb[col];
                v[j] = diff > EPS_W ? diff : 0.f;
            }
        }
    }
    __builtin_nontemporal_store(v, (f32x4*)out + i);
}

extern "C" void kernel_launch(void* const* d_in, const int* in_sizes, int n_in,
                              void* d_out, int out_size, void* d_ws, size_t ws_size,
                              hipStream_t stream) {
    const float* x_feat = (const float*)d_in[0];  // (4,32,256,256) fp32
    const float* x_var  = (const float*)d_in[1];  // (4,1,256,256) fp32
    float* out = (float*)d_out;                   // nodes (524288) ++ adj (67108864)

    float* S  = (float*)d_ws;            // NB*NNODE floats
    float* XV = S + NB * NNODE;          // NB*NNODE floats  (total 128 KiB ws)

    pool_kernel<<<NB * PH, 256, 0, stream>>>(x_feat, x_var, S, XV);
    out_kernel<<<TOTAL_F4 / 256, 256, 0, stream>>>(S, XV, out);
}